// Round 4
// baseline (279.391 us; speedup 1.0000x reference)
//
#include <hip/hip_runtime.h>

// Linear attention, all-fp32, LDS-bandwidth-aware design.
// Per bh: KV[d][c] = sum_s ke[s][d]*ve[s][c]/S ; ksum[d] = sum_s ke[s][d]
//         out[l][c] = S * (qe.KV)[l][c] / (qe.ksum[l] + 1e-6)
//
// r1-r3 lesson: 4x4 thread tiles give 1.0 FLOP per LDS byte; the CU-shared
// LDS pipe (~12 cy per ds_read_b128) then costs ~41 us/phase regardless of
// occupancy or pipelining. This version uses 8x8 register tiles (2.0 FLOP/B,
// half the ds_read instructions): k1 slices s across the 4 waves with one
// end-of-block partial reduction; k3 stages qe transposed so A-reads are
// b128, splits K=64 across 2 thread-groups with one in-LDS reduction.

#define S_LEN 8192
#define NBH 32
#define KVSTRIDE 4160   // 4096 KV + 64 ksum per (bh, chunk)
#define NCHUNK 32       // k1: 1024 blocks, 4 tiles of 64 rows each

typedef __attribute__((ext_vector_type(4))) float f32x4;

__device__ __forceinline__ float elu1(float x) {
  return x > 0.0f ? (x + 1.0f) : __expf(x);
}

// ---------------- Phase 1: partial KV + ksum over a segment of S ----------------
// Staging: all 256 threads, rows dg+16i, cols cg*4 (same as before).
// Compute: wave w owns s-slice [w*16, w*16+16); each lane an 8(d) x 8(c) tile
// covering the full 64x64 output. Reads per s: 2+2 b128 (32B d-octet + 32B
// c-octet, 2-way banks = free) for 128 FMA. End: tree-reduce 4 wave partials.
__global__ __launch_bounds__(256, 4) void k1_partial(
    const float* __restrict__ kin, const float* __restrict__ vin,
    const int* __restrict__ kv_mask, float* __restrict__ partials, int seg_rows) {
  __shared__ float ke_lds[64 * 64];
  __shared__ float ve_lds[64 * 64];
  const int tid = threadIdx.x;
  const int seg = blockIdx.x, bh = blockIdx.y, b = bh >> 3;   // H=8
  const int rbase = seg * seg_rows;
  const int dg = tid >> 4, cg = tid & 15;        // staging roles
  const int w = tid >> 6, lane = tid & 63;
  const int o8 = (lane >> 3) * 8;                // d-octet base
  const int c8 = (lane & 7) * 8;                 // c-octet base
  const float* kbase = kin + (size_t)bh * S_LEN * 64;
  const float* vbase = vin + (size_t)bh * S_LEN * 64;
  const int* mbase = kv_mask + b * S_LEN;

  f32x4 kr[4], vr[4];
  float mr[4];
  float acc[8][8];
#pragma unroll
  for (int i = 0; i < 8; ++i)
#pragma unroll
    for (int j = 0; j < 8; ++j) acc[i][j] = 0.f;
  f32x4 ksump = {0.f, 0.f, 0.f, 0.f};

#define LOAD_T(r0_)                                                    \
  {                                                                    \
    const float* kp_ = kbase + (size_t)(r0_) * 64;                     \
    const float* vp_ = vbase + (size_t)(r0_) * 64;                     \
    _Pragma("unroll")                                                  \
    for (int i_ = 0; i_ < 4; ++i_) {                                   \
      int f_ = tid + 256 * i_;                                         \
      kr[i_] = *(const f32x4*)(kp_ + (size_t)f_ * 4);                  \
      vr[i_] = *(const f32x4*)(vp_ + (size_t)f_ * 4);                  \
      mr[i_] = mbase[(r0_) + dg + 16 * i_] ? 1.0f : 0.0f;              \
    }                                                                  \
  }

#define STORE_T()                                                      \
  {                                                                    \
    _Pragma("unroll")                                                  \
    for (int i_ = 0; i_ < 4; ++i_) {                                   \
      int row_ = dg + 16 * i_;                                         \
      float m_ = mr[i_];                                               \
      float mv_ = m_ * (1.0f / 8192.0f);                               \
      f32x4 ke4_, ve4_;                                                \
      _Pragma("unroll")                                                \
      for (int j_ = 0; j_ < 4; ++j_) {                                 \
        ke4_[j_] = elu1(kr[i_][j_]) * m_;                              \
        ve4_[j_] = vr[i_][j_] * mv_;                                   \
      }                                                                \
      ksump += ke4_;                                                   \
      *(f32x4*)&ke_lds[row_ * 64 + cg * 4] = ke4_;                     \
      *(f32x4*)&ve_lds[row_ * 64 + cg * 4] = ve4_;                     \
    }                                                                  \
  }

#define COMPUTE_T()                                                    \
  {                                                                    \
    _Pragma("unroll 4")                                                \
    for (int ss_ = 0; ss_ < 16; ++ss_) {                               \
      const int s_ = (w << 4) + ss_;                                   \
      f32x4 a0_ = *(const f32x4*)&ke_lds[s_ * 64 + o8];                \
      f32x4 a1_ = *(const f32x4*)&ke_lds[s_ * 64 + o8 + 4];            \
      f32x4 b0_ = *(const f32x4*)&ve_lds[s_ * 64 + c8];                \
      f32x4 b1_ = *(const f32x4*)&ve_lds[s_ * 64 + c8 + 4];            \
      _Pragma("unroll")                                                \
      for (int i_ = 0; i_ < 4; ++i_)                                   \
        _Pragma("unroll")                                              \
        for (int j_ = 0; j_ < 4; ++j_) {                               \
          acc[i_][j_]         = fmaf(a0_[i_], b0_[j_], acc[i_][j_]);   \
          acc[i_][j_ + 4]     = fmaf(a0_[i_], b1_[j_], acc[i_][j_ + 4]); \
          acc[i_ + 4][j_]     = fmaf(a1_[i_], b0_[j_], acc[i_ + 4][j_]); \
          acc[i_ + 4][j_ + 4] = fmaf(a1_[i_], b1_[j_], acc[i_ + 4][j_ + 4]); \
        }                                                              \
    }                                                                  \
  }

  const int ntiles = seg_rows >> 6;   // 4 at NCHUNK=32
  LOAD_T(rbase)
  for (int t = 0; t < ntiles; ++t) {
    if (t) __syncthreads();           // loads for t aged one compute -> cheap drain
    STORE_T()
    __syncthreads();
    if (t + 1 < ntiles) LOAD_T(rbase + (t + 1) * 64)
    COMPUTE_T()                       // covers the loads above
  }

  // ---- reduce 4 wave partials (once per block) ----
#define ACC_W(buf_)                                                    \
  {                                                                    \
    _Pragma("unroll")                                                  \
    for (int i_ = 0; i_ < 8; ++i_)                                     \
      _Pragma("unroll")                                                \
      for (int jq_ = 0; jq_ < 2; ++jq_) {                              \
        f32x4 x_;                                                      \
        _Pragma("unroll")                                              \
        for (int j_ = 0; j_ < 4; ++j_) x_[j_] = acc[i_][jq_ * 4 + j_]; \
        *(f32x4*)&buf_[(o8 + i_) * 64 + c8 + jq_ * 4] = x_;            \
      }                                                                \
  }
#define ACC_A(buf_)                                                    \
  {                                                                    \
    _Pragma("unroll")                                                  \
    for (int i_ = 0; i_ < 8; ++i_)                                     \
      _Pragma("unroll")                                                \
      for (int jq_ = 0; jq_ < 2; ++jq_) {                              \
        f32x4 y_ = *(const f32x4*)&buf_[(o8 + i_) * 64 + c8 + jq_ * 4];\
        _Pragma("unroll")                                              \
        for (int j_ = 0; j_ < 4; ++j_) acc[i_][jq_ * 4 + j_] += y_[j_];\
      }                                                                \
  }

  __syncthreads();                 // all compute done; LDS reusable
  if (w == 2) ACC_W(ke_lds)
  if (w == 3) ACC_W(ve_lds)
  __syncthreads();
  if (w == 0) ACC_A(ke_lds)
  if (w == 1) ACC_A(ve_lds)
  __syncthreads();
  if (w == 1) ACC_W(ke_lds)
  __syncthreads();
  float* p = partials + ((size_t)bh * gridDim.x + seg) * KVSTRIDE;
  if (w == 0) {
    ACC_A(ke_lds)
#pragma unroll
    for (int i = 0; i < 8; ++i)
#pragma unroll
      for (int jq = 0; jq < 2; ++jq) {
        f32x4 o;
#pragma unroll
        for (int j = 0; j < 4; ++j) o[j] = acc[i][jq * 4 + j];
        *(f32x4*)&p[(o8 + i) * 64 + c8 + jq * 4] = o;
      }
  }
  // ksum reduction (ve_lds free after barrier)
  __syncthreads();
  *(f32x4*)&ve_lds[tid * 4] = ksump;
  __syncthreads();
  if (tid < 64) {
    float s = 0.f;
#pragma unroll
    for (int g = 0; g < 16; ++g)
      s += ve_lds[(g * 16 + (tid >> 2)) * 4 + (tid & 3)];
    p[4096 + tid] = s;
  }
#undef LOAD_T
#undef STORE_T
#undef COMPUTE_T
#undef ACC_W
#undef ACC_A
}

// ---------------- Phase 2: reduce partials -> fp32 KV + ksum ----------------
__global__ __launch_bounds__(256) void k2_reduce(
    const float* __restrict__ partials, float* __restrict__ kvg, int nchunk) {
  const int idx = blockIdx.x * 256 + threadIdx.x;
  if (idx >= NBH * KVSTRIDE) return;
  const int bh = idx / KVSTRIDE;
  const int e = idx - bh * KVSTRIDE;
  const float* p = partials + (size_t)bh * nchunk * KVSTRIDE + e;
  float s0 = 0.f, s1 = 0.f, s2 = 0.f, s3 = 0.f;
  int c = 0;
  for (; c + 4 <= nchunk; c += 4) {
    s0 += p[(size_t)(c + 0) * KVSTRIDE];
    s1 += p[(size_t)(c + 1) * KVSTRIDE];
    s2 += p[(size_t)(c + 2) * KVSTRIDE];
    s3 += p[(size_t)(c + 3) * KVSTRIDE];
  }
  for (; c < nchunk; ++c) s0 += p[(size_t)c * KVSTRIDE];
  kvg[idx] = (s0 + s1) + (s2 + s3);
}

// ---------------- Phase 3: out = S * (qe.KV) / (qe.ksum + 1e-6) ----------------
// 2048 one-shot blocks of 128 rows. qe staged TRANSPOSED [d][l] (stride 132) so
// the A-operand is 2 x b128 per d. 2 K-groups x 128 threads, lane tile 8(l)x8(c);
// one 2-way reduction through LDS (reuses the qeT buffer) + den via den_lds.
__global__ __launch_bounds__(256, 3) void k3_out(
    const float* __restrict__ qin, const int* __restrict__ q_mask,
    const float* __restrict__ kvg, float* __restrict__ out) {
  __shared__ float qeT[64 * 132];     // [d][l], l<128, pad 132 for b128 align
  __shared__ float kv_lds[64 * 64];   // [d][c]
  __shared__ float den_lds[128];
  __shared__ float ks_lds[64];
  const int tid = threadIdx.x;
  const int xb = blockIdx.x, bh = blockIdx.y, b = bh >> 3;
  const int r0 = xb * 128;
  const float* kvb = kvg + (size_t)bh * KVSTRIDE;
  const float* qb = qin + ((size_t)bh * S_LEN + r0) * 64;
  const int* mb = q_mask + b * S_LEN + r0;

  // stage KV + ksum (L2-resident, 16KB)
#pragma unroll
  for (int i = 0; i < 4; ++i) {
    int f = tid + 256 * i;
    *(f32x4*)&kv_lds[f * 4] = *(const f32x4*)(kvb + (size_t)f * 4);
  }
  if (tid < 64) ks_lds[tid] = kvb[4096 + tid];

  // stage qe transposed: thread loads 8 row-quads coalesced, scatters to [d][l]
#pragma unroll
  for (int i = 0; i < 8; ++i) {
    int f = tid + 256 * i;
    int row = f >> 4, dq = f & 15;
    float m = mb[row] ? 1.0f : 0.0f;
    f32x4 qw = *(const f32x4*)(qb + (size_t)f * 4);
#pragma unroll
    for (int j = 0; j < 4; ++j)
      qeT[(dq * 4 + j) * 132 + row] = elu1(qw[j]) * m;
  }
  __syncthreads();

  const int g = tid >> 7;           // K-group: d in [g*32, g*32+32)
  const int idx = tid & 127;
  const int l8 = (idx >> 3) * 8;    // row octet
  const int c8 = (idx & 7) * 8;     // col octet
  float acc[8][8];
  float den[8];
#pragma unroll
  for (int i = 0; i < 8; ++i) {
    den[i] = 0.f;
#pragma unroll
    for (int j = 0; j < 8; ++j) acc[i][j] = 0.f;
  }
  const int d0 = g * 32;
#pragma unroll 4
  for (int dd = 0; dd < 32; ++dd) {
    const int d = d0 + dd;
    f32x4 a0 = *(const f32x4*)&qeT[d * 132 + l8];
    f32x4 a1 = *(const f32x4*)&qeT[d * 132 + l8 + 4];
    f32x4 b0 = *(const f32x4*)&kv_lds[d * 64 + c8];
    f32x4 b1 = *(const f32x4*)&kv_lds[d * 64 + c8 + 4];
    float ks = ks_lds[d];
#pragma unroll
    for (int i = 0; i < 4; ++i) {
      den[i]     = fmaf(a0[i], ks, den[i]);
      den[i + 4] = fmaf(a1[i], ks, den[i + 4]);
#pragma unroll
      for (int j = 0; j < 4; ++j) {
        acc[i][j]         = fmaf(a0[i], b0[j], acc[i][j]);
        acc[i][j + 4]     = fmaf(a0[i], b1[j], acc[i][j + 4]);
        acc[i + 4][j]     = fmaf(a1[i], b0[j], acc[i + 4][j]);
        acc[i + 4][j + 4] = fmaf(a1[i], b1[j], acc[i + 4][j + 4]);
      }
    }
  }

  // 2-way K-group reduction through LDS (reuse qeT: 128*64 <= 64*132)
  float* scratch = qeT;
  __syncthreads();
  if (g == 1) {
#pragma unroll
    for (int i = 0; i < 8; ++i)
#pragma unroll
      for (int jq = 0; jq < 2; ++jq) {
        f32x4 x;
#pragma unroll
        for (int j = 0; j < 4; ++j) x[j] = acc[i][jq * 4 + j];
        *(f32x4*)&scratch[(l8 + i) * 64 + c8 + jq * 4] = x;
      }
    if ((idx & 7) == 0) {
#pragma unroll
      for (int i = 0; i < 8; ++i) den_lds[l8 + i] = den[i];
    }
  }
  __syncthreads();
  if (g == 0) {
#pragma unroll
    for (int i = 0; i < 8; ++i) {
      float dv = den[i] + den_lds[l8 + i];
      float inv = 8192.0f / (dv + 1e-6f);
      float* op = out + ((size_t)bh * S_LEN + r0 + l8 + i) * 64 + c8;
#pragma unroll
      for (int jq = 0; jq < 2; ++jq) {
        f32x4 y = *(const f32x4*)&scratch[(l8 + i) * 64 + c8 + jq * 4];
        f32x4 o;
#pragma unroll
        for (int j = 0; j < 4; ++j) o[j] = (acc[i][jq * 4 + j] + y[j]) * inv;
        *(f32x4*)(op + jq * 4) = o;
      }
    }
  }
}

extern "C" void kernel_launch(void* const* d_in, const int* in_sizes, int n_in,
                              void* d_out, int out_size, void* d_ws, size_t ws_size,
                              hipStream_t stream) {
  const float* q = (const float*)d_in[0];
  const float* k = (const float*)d_in[1];
  const float* v = (const float*)d_in[2];
  const int* qm = (const int*)d_in[3];
  const int* km = (const int*)d_in[4];
  float* out = (float*)d_out;

  int nchunk = NCHUNK;
  while (nchunk > 1) {
    size_t need = (size_t)NBH * nchunk * KVSTRIDE * 4 + (size_t)NBH * KVSTRIDE * 4;
    if (need <= ws_size) break;
    nchunk >>= 1;
  }
  float* partials = (float*)d_ws;                           // [NBH][nchunk][KVSTRIDE]
  float* kvg = partials + (size_t)NBH * nchunk * KVSTRIDE;  // [NBH][KVSTRIDE]
  int seg_rows = S_LEN / nchunk;

  k1_partial<<<dim3(nchunk, NBH), 256, 0, stream>>>(k, v, km, partials, seg_rows);
  int n_elem = NBH * KVSTRIDE;
  k2_reduce<<<dim3((n_elem + 255) / 256), 256, 0, stream>>>(partials, kvg, nchunk);
  k3_out<<<dim3(S_LEN / 128, NBH), 256, 0, stream>>>(q, qm, kvg, out);
}

// Round 5
// 255.481 us; speedup vs baseline: 1.0936x; 1.0936x over previous
//
#include <hip/hip_runtime.h>

// Linear attention, all-fp32, 8x8 register tiles (2.0 FLOP per LDS byte).
// Per bh: KV[d][c] = sum_s ke[s][d]*ve[s][c]/S ; ksum[d] = sum_s ke[s][d]
//         out[l][c] = S * (qe.KV)[l][c] / (qe.ksum[l] + 1e-6)
//
// r4 lesson: __launch_bounds__(256,4) + acc[8][8] + 32 prefetch regs = register
// squeeze to 64 VGPR + wholesale accumulator spill (WRITE_SIZE 16.6->128MB).
// This version: plain __launch_bounds__(256) (allocator free, ~100 VGPR ->
// 4-5 waves/SIMD naturally), no cross-barrier prefetch registers (stage loads
// are hoisted by the compiler within the stage phase; cross-block TLP covers
// the per-tile latency). LDS-read amplification 8x (vs 16x at 4x4 tiles):
// ~4.2MB/CU ~ 20us of LDS pipe -> no longer the limiter.

#define S_LEN 8192
#define NBH 32
#define KVSTRIDE 4160   // 4096 KV + 64 ksum per (bh, chunk)
#define NCHUNK 32       // k1: 1024 blocks, 4 tiles of 64 rows each

typedef __attribute__((ext_vector_type(4))) float f32x4;

__device__ __forceinline__ float elu1(float x) {
  return x > 0.0f ? (x + 1.0f) : __expf(x);
}

// ---------------- Phase 1: partial KV + ksum over a segment of S ----------------
// Staging: all 256 threads: rows dg+16i, col-quad cg*4, coalesced b128.
// Compute: wave w owns s-slice [w*16, w*16+16); each lane an 8(d) x 8(c) tile
// of the full 64x64 output (acc=64 regs). End: tree-reduce 4 wave partials.
__global__ __launch_bounds__(256) void k1_partial(
    const float* __restrict__ kin, const float* __restrict__ vin,
    const int* __restrict__ kv_mask, float* __restrict__ partials, int seg_rows) {
  __shared__ float ke_lds[64 * 64];
  __shared__ float ve_lds[64 * 64];
  const int tid = threadIdx.x;
  const int seg = blockIdx.x, bh = blockIdx.y, b = bh >> 3;   // H=8
  const int rbase = seg * seg_rows;
  const int dg = tid >> 4, cg = tid & 15;        // staging roles
  const int w = tid >> 6, lane = tid & 63;
  const int o8 = (lane >> 3) * 8;                // d-octet base
  const int c8 = (lane & 7) * 8;                 // c-octet base
  const float* kbase = kin + (size_t)bh * S_LEN * 64;
  const float* vbase = vin + (size_t)bh * S_LEN * 64;
  const int* mbase = kv_mask + b * S_LEN;

  float acc[8][8];
#pragma unroll
  for (int i = 0; i < 8; ++i)
#pragma unroll
    for (int j = 0; j < 8; ++j) acc[i][j] = 0.f;
  f32x4 ksump = {0.f, 0.f, 0.f, 0.f};

  const int ntiles = seg_rows >> 6;   // 4 at NCHUNK=32
  for (int t = 0; t < ntiles; ++t) {
    const int r0 = rbase + t * 64;
    if (t) __syncthreads();           // prev compute done reading LDS
    // ---- stage: load + transform + LDS write (loads hoisted by compiler) ----
#pragma unroll
    for (int i = 0; i < 4; ++i) {
      const int f = tid + 256 * i;
      const int row = dg + 16 * i;
      f32x4 k4 = *(const f32x4*)(kbase + (size_t)(r0) * 64 + (size_t)f * 4);
      f32x4 v4 = *(const f32x4*)(vbase + (size_t)(r0) * 64 + (size_t)f * 4);
      float m = mbase[r0 + row] ? 1.0f : 0.0f;
      float mv = m * (1.0f / 8192.0f);
      f32x4 ke4, ve4;
#pragma unroll
      for (int j = 0; j < 4; ++j) {
        ke4[j] = elu1(k4[j]) * m;
        ve4[j] = v4[j] * mv;
      }
      ksump += ke4;
      *(f32x4*)&ke_lds[row * 64 + cg * 4] = ke4;
      *(f32x4*)&ve_lds[row * 64 + cg * 4] = ve4;
    }
    __syncthreads();
    // ---- compute: 16 s per wave, 4 b128 reads + 64 FMA per s ----
#pragma unroll 4
    for (int ss = 0; ss < 16; ++ss) {
      const int s = (w << 4) + ss;
      f32x4 a0 = *(const f32x4*)&ke_lds[s * 64 + o8];
      f32x4 a1 = *(const f32x4*)&ke_lds[s * 64 + o8 + 4];
      f32x4 b0 = *(const f32x4*)&ve_lds[s * 64 + c8];
      f32x4 b1 = *(const f32x4*)&ve_lds[s * 64 + c8 + 4];
#pragma unroll
      for (int i = 0; i < 4; ++i)
#pragma unroll
        for (int j = 0; j < 4; ++j) {
          acc[i][j]         = fmaf(a0[i], b0[j], acc[i][j]);
          acc[i][j + 4]     = fmaf(a0[i], b1[j], acc[i][j + 4]);
          acc[i + 4][j]     = fmaf(a1[i], b0[j], acc[i + 4][j]);
          acc[i + 4][j + 4] = fmaf(a1[i], b1[j], acc[i + 4][j + 4]);
        }
    }
  }

  // ---- reduce 4 wave partials (once per block) ----
#define ACC_W(buf_)                                                    \
  {                                                                    \
    _Pragma("unroll")                                                  \
    for (int i_ = 0; i_ < 8; ++i_)                                     \
      _Pragma("unroll")                                                \
      for (int jq_ = 0; jq_ < 2; ++jq_) {                              \
        f32x4 x_;                                                      \
        _Pragma("unroll")                                              \
        for (int j_ = 0; j_ < 4; ++j_) x_[j_] = acc[i_][jq_ * 4 + j_]; \
        *(f32x4*)&buf_[(o8 + i_) * 64 + c8 + jq_ * 4] = x_;            \
      }                                                                \
  }
#define ACC_A(buf_)                                                    \
  {                                                                    \
    _Pragma("unroll")                                                  \
    for (int i_ = 0; i_ < 8; ++i_)                                     \
      _Pragma("unroll")                                                \
      for (int jq_ = 0; jq_ < 2; ++jq_) {                              \
        f32x4 y_ = *(const f32x4*)&buf_[(o8 + i_) * 64 + c8 + jq_ * 4];\
        _Pragma("unroll")                                              \
        for (int j_ = 0; j_ < 4; ++j_) acc[i_][jq_ * 4 + j_] += y_[j_];\
      }                                                                \
  }

  __syncthreads();                 // all compute done; LDS reusable
  if (w == 2) ACC_W(ke_lds)
  if (w == 3) ACC_W(ve_lds)
  __syncthreads();
  if (w == 0) ACC_A(ke_lds)
  if (w == 1) ACC_A(ve_lds)
  __syncthreads();
  if (w == 1) ACC_W(ke_lds)
  __syncthreads();
  float* p = partials + ((size_t)bh * gridDim.x + seg) * KVSTRIDE;
  if (w == 0) {
    ACC_A(ke_lds)
#pragma unroll
    for (int i = 0; i < 8; ++i)
#pragma unroll
      for (int jq = 0; jq < 2; ++jq) {
        f32x4 o;
#pragma unroll
        for (int j = 0; j < 4; ++j) o[j] = acc[i][jq * 4 + j];
        *(f32x4*)&p[(o8 + i) * 64 + c8 + jq * 4] = o;
      }
  }
  // ksum reduction (ve_lds free after barrier)
  __syncthreads();
  *(f32x4*)&ve_lds[tid * 4] = ksump;
  __syncthreads();
  if (tid < 64) {
    float s = 0.f;
#pragma unroll
    for (int g = 0; g < 16; ++g)
      s += ve_lds[(g * 16 + (tid >> 2)) * 4 + (tid & 3)];
    p[4096 + tid] = s;
  }
#undef ACC_W
#undef ACC_A
}

// ---------------- Phase 2: reduce partials -> fp32 KV + ksum ----------------
__global__ __launch_bounds__(256) void k2_reduce(
    const float* __restrict__ partials, float* __restrict__ kvg, int nchunk) {
  const int idx = blockIdx.x * 256 + threadIdx.x;
  if (idx >= NBH * KVSTRIDE) return;
  const int bh = idx / KVSTRIDE;
  const int e = idx - bh * KVSTRIDE;
  const float* p = partials + (size_t)bh * nchunk * KVSTRIDE + e;
  float s0 = 0.f, s1 = 0.f, s2 = 0.f, s3 = 0.f;
  int c = 0;
  for (; c + 4 <= nchunk; c += 4) {
    s0 += p[(size_t)(c + 0) * KVSTRIDE];
    s1 += p[(size_t)(c + 1) * KVSTRIDE];
    s2 += p[(size_t)(c + 2) * KVSTRIDE];
    s3 += p[(size_t)(c + 3) * KVSTRIDE];
  }
  for (; c < nchunk; ++c) s0 += p[(size_t)c * KVSTRIDE];
  kvg[idx] = (s0 + s1) + (s2 + s3);
}

// ---------------- Phase 3: out = S * (qe.KV) / (qe.ksum + 1e-6) ----------------
// 2048 one-shot blocks of 128 rows. qe staged TRANSPOSED [d][l] (stride 132) so
// the A-operand is 2 x b128 per d. 2 K-groups x 128 threads, lane tile 8(l)x8(c);
// one 2-way reduction through LDS (reuses the qeT buffer) + den via den_lds.
__global__ __launch_bounds__(256) void k3_out(
    const float* __restrict__ qin, const int* __restrict__ q_mask,
    const float* __restrict__ kvg, float* __restrict__ out) {
  __shared__ float qeT[64 * 132];     // [d][l], l<128, pad 132 for b128 align
  __shared__ float kv_lds[64 * 64];   // [d][c]
  __shared__ float den_lds[128];
  __shared__ float ks_lds[64];
  const int tid = threadIdx.x;
  const int xb = blockIdx.x, bh = blockIdx.y, b = bh >> 3;
  const int r0 = xb * 128;
  const float* kvb = kvg + (size_t)bh * KVSTRIDE;
  const float* qb = qin + ((size_t)bh * S_LEN + r0) * 64;
  const int* mb = q_mask + b * S_LEN + r0;

  // stage KV + ksum (L2-resident, 16KB)
#pragma unroll
  for (int i = 0; i < 4; ++i) {
    int f = tid + 256 * i;
    *(f32x4*)&kv_lds[f * 4] = *(const f32x4*)(kvb + (size_t)f * 4);
  }
  if (tid < 64) ks_lds[tid] = kvb[4096 + tid];

  // stage qe transposed: thread loads 8 row-quads coalesced, scatters to [d][l]
#pragma unroll
  for (int i = 0; i < 8; ++i) {
    int f = tid + 256 * i;
    int row = f >> 4, dq = f & 15;
    float m = mb[row] ? 1.0f : 0.0f;
    f32x4 qw = *(const f32x4*)(qb + (size_t)f * 4);
#pragma unroll
    for (int j = 0; j < 4; ++j)
      qeT[(dq * 4 + j) * 132 + row] = elu1(qw[j]) * m;
  }
  __syncthreads();

  const int g = tid >> 7;           // K-group: d in [g*32, g*32+32)
  const int idx = tid & 127;
  const int l8 = (idx >> 3) * 8;    // row octet
  const int c8 = (idx & 7) * 8;     // col octet
  float acc[8][8];
  float den[8];
#pragma unroll
  for (int i = 0; i < 8; ++i) {
    den[i] = 0.f;
#pragma unroll
    for (int j = 0; j < 8; ++j) acc[i][j] = 0.f;
  }
  const int d0 = g * 32;
#pragma unroll 4
  for (int dd = 0; dd < 32; ++dd) {
    const int d = d0 + dd;
    f32x4 a0 = *(const f32x4*)&qeT[d * 132 + l8];
    f32x4 a1 = *(const f32x4*)&qeT[d * 132 + l8 + 4];
    f32x4 b0 = *(const f32x4*)&kv_lds[d * 64 + c8];
    f32x4 b1 = *(const f32x4*)&kv_lds[d * 64 + c8 + 4];
    float ks = ks_lds[d];
#pragma unroll
    for (int i = 0; i < 4; ++i) {
      den[i]     = fmaf(a0[i], ks, den[i]);
      den[i + 4] = fmaf(a1[i], ks, den[i + 4]);
#pragma unroll
      for (int j = 0; j < 4; ++j) {
        acc[i][j]         = fmaf(a0[i], b0[j], acc[i][j]);
        acc[i][j + 4]     = fmaf(a0[i], b1[j], acc[i][j + 4]);
        acc[i + 4][j]     = fmaf(a1[i], b0[j], acc[i + 4][j]);
        acc[i + 4][j + 4] = fmaf(a1[i], b1[j], acc[i + 4][j + 4]);
      }
    }
  }

  // 2-way K-group reduction through LDS (reuse qeT: 128*64 <= 64*132)
  float* scratch = qeT;
  __syncthreads();
  if (g == 1) {
#pragma unroll
    for (int i = 0; i < 8; ++i)
#pragma unroll
      for (int jq = 0; jq < 2; ++jq) {
        f32x4 x;
#pragma unroll
        for (int j = 0; j < 4; ++j) x[j] = acc[i][jq * 4 + j];
        *(f32x4*)&scratch[(l8 + i) * 64 + c8 + jq * 4] = x;
      }
    if ((idx & 7) == 0) {
#pragma unroll
      for (int i = 0; i < 8; ++i) den_lds[l8 + i] = den[i];
    }
  }
  __syncthreads();
  if (g == 0) {
#pragma unroll
    for (int i = 0; i < 8; ++i) {
      float dv = den[i] + den_lds[l8 + i];
      float inv = 8192.0f / (dv + 1e-6f);
      float* op = out + ((size_t)bh * S_LEN + r0 + l8 + i) * 64 + c8;
#pragma unroll
      for (int jq = 0; jq < 2; ++jq) {
        f32x4 y = *(const f32x4*)&scratch[(l8 + i) * 64 + c8 + jq * 4];
        f32x4 o;
#pragma unroll
        for (int j = 0; j < 4; ++j) o[j] = (acc[i][jq * 4 + j] + y[j]) * inv;
        *(f32x4*)(op + jq * 4) = o;
      }
    }
  }
}

extern "C" void kernel_launch(void* const* d_in, const int* in_sizes, int n_in,
                              void* d_out, int out_size, void* d_ws, size_t ws_size,
                              hipStream_t stream) {
  const float* q = (const float*)d_in[0];
  const float* k = (const float*)d_in[1];
  const float* v = (const float*)d_in[2];
  const int* qm = (const int*)d_in[3];
  const int* km = (const int*)d_in[4];
  float* out = (float*)d_out;

  int nchunk = NCHUNK;
  while (nchunk > 1) {
    size_t need = (size_t)NBH * nchunk * KVSTRIDE * 4 + (size_t)NBH * KVSTRIDE * 4;
    if (need <= ws_size) break;
    nchunk >>= 1;
  }
  float* partials = (float*)d_ws;                           // [NBH][nchunk][KVSTRIDE]
  float* kvg = partials + (size_t)NBH * nchunk * KVSTRIDE;  // [NBH][KVSTRIDE]
  int seg_rows = S_LEN / nchunk;

  k1_partial<<<dim3(nchunk, NBH), 256, 0, stream>>>(k, v, km, partials, seg_rows);
  int n_elem = NBH * KVSTRIDE;
  k2_reduce<<<dim3((n_elem + 255) / 256), 256, 0, stream>>>(partials, kvg, nchunk);
  k3_out<<<dim3(S_LEN / 128, NBH), 256, 0, stream>>>(q, qm, kvg, out);
}